// Round 9
// baseline (987.571 us; speedup 1.0000x reference)
//
#include <hip/hip_runtime.h>
#include <math.h>

#define Bn   4
#define CINn 16
#define HIDn 16
#define Tn   31
#define Hn   128
#define Wn   128

#define NS   14                   // K-steps: 28 taps (27 real + 1 zero-pad) x 16 cin, K=32 each

typedef _Float16 half8 __attribute__((ext_vector_type(8)));
typedef float    f32x4 __attribute__((ext_vector_type(4)));

// tap = kd*9 + kh*3 + kw ; entry 27 is an address clamp (its weight is 0)
constexpr int KDt[28] = {0,0,0,0,0,0,0,0,0, 1,1,1,1,1,1,1,1,1, 2,2,2,2,2,2,2,2,2, 2};
constexpr int KHt[28] = {0,0,0,1,1,1,2,2,2, 0,0,0,1,1,1,2,2,2, 0,0,0,1,1,1,2,2,2, 2};
constexpr int KWt[28] = {0,1,2,0,1,2,0,1,2, 0,1,2,0,1,2,0,1,2, 0,1,2,0,1,2,0,1,2, 2};

__device__ __forceinline__ float sigmoidf_(float x) { return 1.f / (1.f + __expf(-x)); }
__device__ __forceinline__ float tanhf_(float x)    { return 2.f / (1.f + __expf(-2.f * x)) - 1.f; }

// Repack W[oc][cin][kd][kh][kw] into per-lane A-fragment layout, f16 (both paths):
// WA[s][m][lane][j] : g = lane>>4 ; tap = 2s + (g>>1) ; cin = (g&1)*8 + j ; oc = m*16 + (lane&15)
__global__ void repack_wa_kernel(const float* __restrict__ W, _Float16* __restrict__ WA) {
    int idx = blockIdx.x * blockDim.x + threadIdx.x;
    if (idx >= NS * 4 * 64 * 8) return;
    int j    = idx & 7;
    int lane = (idx >> 3) & 63;
    int m    = (idx >> 9) & 3;
    int s    = idx >> 11;
    int g    = lane >> 4;
    int tap  = 2 * s + (g >> 1);
    int cin  = (g & 1) * 8 + j;
    int oc   = m * 16 + (lane & 15);
    float v  = (tap < 27) ? W[(size_t)(oc * CINn + cin) * 27 + tap] : 0.f;
    WA[idx] = (_Float16)v;
}

// =====================  FAST PATH  =====================
#define POSB    48                  // 16 cin f16 (32 B) + 16 B pad: 16-lane stride-48 -> 2-way banks (free)
#define NWPOS   66                  // 64 w + 2 halo
#define ROWF    (NWPOS*POSB)        // 3168 B per staged row
#define SLOTF   (3*ROWF)            // 9504 B per time slice (rows h-1..h+1)
#define LDSF    (4*SLOTF)           // 38016 B: 4-slot ring -> single barrier per t
#define NPOS    (3*NWPOS)           // 198 staging positions, 1 per thread
// WA = 14*4*64*8 f16 = 28672 ELEMENTS = 57344 BYTES (XH_OFF must clear it)
#define XH_OFF  65536
#define SLICE_B (Hn*Wn*CINn*2)      // 524288 B per (b,t) slice
#define WS_NEED ((size_t)XH_OFF + (size_t)Bn*Tn*SLICE_B)

// X[b][cin][t][h][w] f32 -> Xh[b][t][h][w][cin] f16 (cin contiguous, 16B-load-able)
__global__ __launch_bounds__(256)
void transpose_x_kernel(const float* __restrict__ X, _Float16* __restrict__ Xh) {
    int i   = blockIdx.x * 256 + threadIdx.x;      // over Bn*Tn*Hn*Wn = 2,031,616 (exact grid)
    int pos = i & 16383;
    int bu  = i >> 14;                             // b*31 + u
    int b   = bu / 31;
    int u   = bu - b * 31;
    const float* src = X + ((size_t)(b * CINn) * Tn + u) * 16384 + pos;
    half8 h0, h1;
    #pragma unroll
    for (int c = 0; c < 8; c++) h0[c] = (_Float16)src[(size_t)c * (Tn * 16384)];
    #pragma unroll
    for (int c = 0; c < 8; c++) h1[c] = (_Float16)src[(size_t)(c + 8) * (Tn * 16384)];
    half8* dst = (half8*)(Xh + (size_t)i * 16);
    dst[0] = h0; dst[1] = h1;
}

// One workgroup per (b, h, w-half): 1024 wgs -> 4 wgs/CU x 4 waves = 16 waves/CU
// (round 8 was grid-capped at 2 wgs/CU = 22% occupancy; this doubles TLP).
// 256 threads = 4 waves; wave = 1 n-tile (16 w) x 4 oc-tiles. Staging: 1 position
// per thread (198 used) from pre-transposed f16 Xh. 4-slot ring, ONE barrier per
// t; t+2 prefetch issued after the barrier stays in flight across full compute.
__global__ __launch_bounds__(256, 4)
void qrnn_xh_kernel(const _Float16* __restrict__ Xh, const _Float16* __restrict__ WA,
                    const float* __restrict__ bias, float* __restrict__ out) {
    __shared__ __align__(16) char smem[LDSF];

    const int tid  = threadIdx.x;
    const int lane = tid & 63;
    const int wv   = tid >> 6;            // wave 0..3 -> w sub-segment [wv*16, wv*16+16)

    // XCD-bijective swizzle (1024 wgs, 8 XCDs): each XCD gets 64 contiguous h x 2 halves
    const int swz = (blockIdx.x & 7) * 128 + (blockIdx.x >> 3);
    const int b    = swz >> 8;
    const int h    = (swz >> 1) & 127;
    const int wh   = swz & 1;
    const int woff = wh * 64;

    const size_t strideT = (size_t)Hn * Wn;        // 16384
    const size_t strideC = (size_t)Tn * strideT;   // 507904

    const int lane15 = lane & 15;
    const int g      = lane >> 4;         // k-group 0..3
    const int ghi    = g >> 1;            // tap within K-step pair
    const int e      = g & 1;             // cin half
    const int wloc   = wv * 16 + lane15;  // local w column 0..63
    const int pbase  = wloc * POSB + e * 16;

    // bias per thread: hid = g*4 + r (C-frag row = (lane>>4)*4 + reg)
    float bz[4], bfv[4], bov[4], biv[4];
    #pragma unroll
    for (int r = 0; r < 4; r++) {
        int hid = g * 4 + r;
        bz[r]  = bias[hid];
        bfv[r] = bias[HIDn + hid];
        bov[r] = bias[2 * HIDn + hid];
        biv[r] = bias[3 * HIDn + hid];
    }

    // --- staging: 198 positions (3 rows x 66 wpos), exactly one per thread ---
    const char* XhB = (const char*)Xh + (size_t)b * Tn * SLICE_B;
    const bool own  = (tid < NPOS);
    const int  srow = tid / NWPOS;                 // 0..2
    const int  swp  = tid - srow * NWPOS;          // 0..65
    const int  hr   = h - 1 + srow;
    const int  wa   = woff - 1 + swp;              // global w of this position
    const bool inb  = own && (hr >= 0) && (hr < Hn) && (wa >= 0) && (wa < Wn);
    const int  soff = (hr * Wn + wa) * 32;
    const int  loff = srow * ROWF + swp * POSB;

    half8 pfA, pfB;     // in-flight slice data (already f16, no cvt)

    auto issue = [&](int u) {
        half8 a = {}, c = {};
        if (inb && u >= 0 && u < Tn) {
            const char* s = XhB + (size_t)u * SLICE_B + soff;
            a = *reinterpret_cast<const half8*>(s);
            c = *reinterpret_cast<const half8*>(s + 16);
        }
        pfA = a; pfB = c;
    };
    auto commit = [&](int u) {
        if (own) {
            char* dst = smem + (u & 3) * SLOTF + loff;
            *reinterpret_cast<half8*>(dst)      = pfA;
            *reinterpret_cast<half8*>(dst + 16) = pfB;
        }
    };

    // prologue: slot 3 (u=-1) = zeros; commit u=0; issue u=1
    if (own) {
        half8 z = {};
        char* dst = smem + 3 * SLOTF + loff;
        *reinterpret_cast<half8*>(dst)      = z;
        *reinterpret_cast<half8*>(dst + 16) = z;
    }
    issue(0);
    commit(0);
    issue(1);

    float cst[4] = {0.f, 0.f, 0.f, 0.f};
    float* outb = out + (size_t)b * HIDn * strideC + (size_t)h * Wn + woff + wloc;

    for (int t = 0; t < Tn; t++) {
        commit(t + 1);                 // pf (loaded last iter) -> slot (t+1)&3
        __syncthreads();               // lgkm drain publishes it; ring safety
        issue(t + 2);                  // loads in flight across full compute phase

        const int sb[3] = { ((t + 3) & 3) * SLOTF, (t & 3) * SLOTF, ((t + 1) & 3) * SLOTF };

        f32x4 acc[4];
        #pragma unroll
        for (int m = 0; m < 4; m++) acc[m] = (f32x4)(0.f);

        #pragma unroll
        for (int s = 0; s < NS; s++) {
            const half8 a0 = *reinterpret_cast<const half8*>(WA + ((size_t)(s * 4 + 0) * 64 + lane) * 8);
            const half8 a1 = *reinterpret_cast<const half8*>(WA + ((size_t)(s * 4 + 1) * 64 + lane) * 8);
            const half8 a2 = *reinterpret_cast<const half8*>(WA + ((size_t)(s * 4 + 2) * 64 + lane) * 8);
            const half8 a3 = *reinterpret_cast<const half8*>(WA + ((size_t)(s * 4 + 3) * 64 + lane) * 8);

            const int tA = 2 * s, tB = 2 * s + 1;        // compile-time taps
            const int offA = sb[KDt[tA]] + KHt[tA] * ROWF + KWt[tA] * POSB;
            const int offB = sb[KDt[tB]] + KHt[tB] * ROWF + KWt[tB] * POSB;
            const int off  = (ghi ? offB : offA) + pbase;

            const half8 bf = *reinterpret_cast<const half8*>(smem + off);
            acc[0] = __builtin_amdgcn_mfma_f32_16x16x32_f16(a0, bf, acc[0], 0, 0, 0);
            acc[1] = __builtin_amdgcn_mfma_f32_16x16x32_f16(a1, bf, acc[1], 0, 0, 0);
            acc[2] = __builtin_amdgcn_mfma_f32_16x16x32_f16(a2, bf, acc[2], 0, 0, 0);
            acc[3] = __builtin_amdgcn_mfma_f32_16x16x32_f16(a3, bf, acc[3], 0, 0, 0);
        }

        // epilogue: oc-tile m = gate m (z,f,o,i) for hid = g*4+r, col = woff+wloc
        #pragma unroll
        for (int r = 0; r < 4; r++) {
            float z = tanhf_   (acc[0][r] + bz[r]);
            float f = sigmoidf_(acc[1][r] + bfv[r]);
            float o = sigmoidf_(acc[2][r] + bov[r]);
            float i = sigmoidf_(acc[3][r] + biv[r]);
            float c = f * cst[r] + i * z;
            cst[r] = c;
            outb[(size_t)(g * 4 + r) * strideC + (size_t)t * strideT] = o * c;
        }
        // no trailing barrier: 4-slot ring keeps next iter's writes disjoint from
        // any slot a <=1-iteration-lagging wave can still be reading.
    }
}

// =====================  FALLBACK (round-1 harness-verified; used if ws too small)  =====================
#define WSTR  48
#define ROWB  (130*WSTR)
#define SLOT3 (3*ROWB)
#define LDS3  (3*SLOT3)

__global__ __launch_bounds__(256, 2)
void qrnn_fb_kernel(const float* __restrict__ X, const _Float16* __restrict__ WA,
                    const float* __restrict__ bias, float* __restrict__ out) {
    __shared__ __align__(16) char smem[LDS3];
    const int tid  = threadIdx.x;
    const int lane = tid & 63;
    const int wv   = tid >> 6;
    const int swz = (blockIdx.x & 7) * 64 + (blockIdx.x >> 3);
    const int b = swz >> 7;
    const int h = swz & 127;
    const size_t strideT = (size_t)Hn * Wn;
    const size_t strideC = (size_t)Tn * strideT;
    const float* Xb = X + (size_t)b * CINn * strideC;
    const int lane15  = lane & 15;
    const int g       = lane >> 4;
    const int ghi     = g >> 1;
    const int laneoff = lane15 * WSTR + (g & 1) * 16;
    const int wbase   = wv * 32;
    float bz[4], bfv[4], bov[4], biv[4];
    #pragma unroll
    for (int r = 0; r < 4; r++) {
        int hid = g * 4 + r;
        bz[r] = bias[hid]; bfv[r] = bias[HIDn + hid];
        bov[r] = bias[2 * HIDn + hid]; biv[r] = bias[3 * HIDn + hid];
    }
    auto stage = [&](int u, int s) {
        const bool uok = (u >= 0) && (u < Tn);
        for (int p = tid; p < 3 * 130; p += 256) {
            int row  = (p >= 260) ? 2 : (p >= 130) ? 1 : 0;
            int wpos = p - row * 130;
            int hr = h - 1 + row;
            int wa = wpos - 1;
            bool valid = uok && (hr >= 0) && (hr < Hn) && (wa >= 0) && (wa < Wn);
            const float* src = Xb + (ptrdiff_t)u * (ptrdiff_t)strideT + (ptrdiff_t)hr * Wn + wa;
            half8 h0, h1;
            #pragma unroll
            for (int c8 = 0; c8 < 8; c8++) h0[c8] = valid ? (_Float16)src[(size_t)c8 * strideC] : (_Float16)0.f;
            #pragma unroll
            for (int c8 = 0; c8 < 8; c8++) h1[c8] = valid ? (_Float16)src[(size_t)(8 + c8) * strideC] : (_Float16)0.f;
            char* dst = smem + s * SLOT3 + row * ROWB + wpos * WSTR;
            *reinterpret_cast<half8*>(dst)      = h0;
            *reinterpret_cast<half8*>(dst + 16) = h1;
        }
    };
    float cst[2][4];
    #pragma unroll
    for (int n = 0; n < 2; n++)
        #pragma unroll
        for (int r = 0; r < 4; r++) cst[n][r] = 0.f;
    stage(-1, 2);
    stage(0, 0);
    float* outb = out + (size_t)b * HIDn * strideC + (size_t)h * Wn + wbase + lane15;
    for (int t = 0; t < Tn; t++) {
        stage(t + 1, (t + 1) % 3);
        __syncthreads();
        const int sb[3] = { ((t + 2) % 3) * SLOT3, (t % 3) * SLOT3, ((t + 1) % 3) * SLOT3 };
        f32x4 acc[2][4];
        #pragma unroll
        for (int n = 0; n < 2; n++)
            #pragma unroll
            for (int m = 0; m < 4; m++) acc[n][m] = (f32x4)(0.f);
        #pragma unroll
        for (int s = 0; s < NS; s++) {
            const half8 a0 = *reinterpret_cast<const half8*>(WA + ((size_t)(s * 4 + 0) * 64 + lane) * 8);
            const half8 a1 = *reinterpret_cast<const half8*>(WA + ((size_t)(s * 4 + 1) * 64 + lane) * 8);
            const half8 a2 = *reinterpret_cast<const half8*>(WA + ((size_t)(s * 4 + 2) * 64 + lane) * 8);
            const half8 a3 = *reinterpret_cast<const half8*>(WA + ((size_t)(s * 4 + 3) * 64 + lane) * 8);
            const int tA = 2 * s, tB = 2 * s + 1;
            const int offA = sb[KDt[tA]] + KHt[tA] * ROWB + KWt[tA] * WSTR;
            const int offB = sb[KDt[tB]] + KHt[tB] * ROWB + KWt[tB] * WSTR;
            const int off  = (ghi ? offB : offA) + laneoff;
            #pragma unroll
            for (int n = 0; n < 2; n++) {
                const half8 bf = *reinterpret_cast<const half8*>(smem + off + (wbase + n * 16) * WSTR);
                acc[n][0] = __builtin_amdgcn_mfma_f32_16x16x32_f16(a0, bf, acc[n][0], 0, 0, 0);
                acc[n][1] = __builtin_amdgcn_mfma_f32_16x16x32_f16(a1, bf, acc[n][1], 0, 0, 0);
                acc[n][2] = __builtin_amdgcn_mfma_f32_16x16x32_f16(a2, bf, acc[n][2], 0, 0, 0);
                acc[n][3] = __builtin_amdgcn_mfma_f32_16x16x32_f16(a3, bf, acc[n][3], 0, 0, 0);
            }
        }
        #pragma unroll
        for (int n = 0; n < 2; n++) {
            #pragma unroll
            for (int r = 0; r < 4; r++) {
                float z = tanhf_   (acc[n][0][r] + bz[r]);
                float f = sigmoidf_(acc[n][1][r] + bfv[r]);
                float o = sigmoidf_(acc[n][2][r] + bov[r]);
                float i = sigmoidf_(acc[n][3][r] + biv[r]);
                float c = f * cst[n][r] + i * z;
                cst[n][r] = c;
                outb[(size_t)(g * 4 + r) * strideC + (size_t)t * strideT + n * 16] = o * c;
            }
        }
        __syncthreads();
    }
}

// =====================  host  =====================
extern "C" void kernel_launch(void* const* d_in, const int* in_sizes, int n_in,
                              void* d_out, int out_size, void* d_ws, size_t ws_size,
                              hipStream_t stream) {
    const float* X    = (const float*)d_in[0];
    const float* W    = (const float*)d_in[1];
    const float* bias = (const float*)d_in[2];
    float* out = (float*)d_out;

    _Float16* WA = (_Float16*)d_ws;   // 28672 f16 = 57344 BYTES (ends < XH_OFF)
    repack_wa_kernel<<<(NS * 4 * 64 * 8 + 255) / 256, 256, 0, stream>>>(W, WA);

    if (ws_size >= WS_NEED) {
        _Float16* Xh = (_Float16*)((char*)d_ws + XH_OFF);
        transpose_x_kernel<<<(Bn * Tn * Hn * Wn) / 256, 256, 0, stream>>>(X, Xh);
        qrnn_xh_kernel<<<Bn * Hn * 2, 256, 0, stream>>>(Xh, WA, bias, out);
    } else {
        qrnn_fb_kernel<<<Bn * Hn, 256, 0, stream>>>(X, WA, bias, out);
    }
}

// Round 10
// 486.229 us; speedup vs baseline: 2.0311x; 2.0311x over previous
//
#include <hip/hip_runtime.h>
#include <math.h>

#define Bn   4
#define CINn 16
#define HIDn 16
#define Tn   31
#define Hn   128
#define Wn   128

#define NS   14                   // K-steps: 28 taps (27 real + 1 zero-pad) x 16 cin, K=32 each

typedef _Float16 half8 __attribute__((ext_vector_type(8)));
typedef float    f32x4 __attribute__((ext_vector_type(4)));

// tap = kd*9 + kh*3 + kw ; entry 27 is an address clamp (its weight is 0)
constexpr int KDt[28] = {0,0,0,0,0,0,0,0,0, 1,1,1,1,1,1,1,1,1, 2,2,2,2,2,2,2,2,2, 2};
constexpr int KHt[28] = {0,0,0,1,1,1,2,2,2, 0,0,0,1,1,1,2,2,2, 0,0,0,1,1,1,2,2,2, 2};
constexpr int KWt[28] = {0,1,2,0,1,2,0,1,2, 0,1,2,0,1,2,0,1,2, 0,1,2,0,1,2,0,1,2, 2};

__device__ __forceinline__ float sigmoidf_(float x) { return 1.f / (1.f + __expf(-x)); }
__device__ __forceinline__ float tanhf_(float x)    { return 2.f / (1.f + __expf(-2.f * x)) - 1.f; }

// Repack W[oc][cin][kd][kh][kw] into per-lane A-fragment layout, f16 (both paths):
// WA[s][m][lane][j] : g = lane>>4 ; tap = 2s + (g>>1) ; cin = (g&1)*8 + j ; oc = m*16 + (lane&15)
__global__ void repack_wa_kernel(const float* __restrict__ W, _Float16* __restrict__ WA) {
    int idx = blockIdx.x * blockDim.x + threadIdx.x;
    if (idx >= NS * 4 * 64 * 8) return;
    int j    = idx & 7;
    int lane = (idx >> 3) & 63;
    int m    = (idx >> 9) & 3;
    int s    = idx >> 11;
    int g    = lane >> 4;
    int tap  = 2 * s + (g >> 1);
    int cin  = (g & 1) * 8 + j;
    int oc   = m * 16 + (lane & 15);
    float v  = (tap < 27) ? W[(size_t)(oc * CINn + cin) * 27 + tap] : 0.f;
    WA[idx] = (_Float16)v;
}

// =====================  FAST PATH  =====================
#define POSB    48                  // 16 cin f16 (32 B) + 16 B pad: 16-lane stride-48 -> 2-way banks (free)
#define NWPOS   66                  // 64 w + 2 halo
#define ROWF    (NWPOS*POSB)        // 3168 B per staged row
#define SLOTF   (3*ROWF)            // 9504 B per time slice (rows h-1..h+1)
#define LDSF    (4*SLOTF)           // 38016 B: 4-slot ring -> single barrier per t
#define NPOS    (3*NWPOS)           // 198 staging positions, 1 per thread
// WA = 14*4*64*8 f16 = 28672 ELEMENTS = 57344 BYTES (XH_OFF must clear it)
#define XH_OFF  65536
#define SLICE_B (Hn*Wn*CINn*2)      // 524288 B per (b,t) slice
#define WS_NEED ((size_t)XH_OFF + (size_t)Bn*Tn*SLICE_B)

// X[b][cin][t][h][w] f32 -> Xh[b][t][h][w][cin] f16 (cin contiguous, 16B-load-able)
__global__ __launch_bounds__(256)
void transpose_x_kernel(const float* __restrict__ X, _Float16* __restrict__ Xh) {
    int i   = blockIdx.x * 256 + threadIdx.x;      // over Bn*Tn*Hn*Wn = 2,031,616 (exact grid)
    int pos = i & 16383;
    int bu  = i >> 14;                             // b*31 + u
    int b   = bu / 31;
    int u   = bu - b * 31;
    const float* src = X + ((size_t)(b * CINn) * Tn + u) * 16384 + pos;
    half8 h0, h1;
    #pragma unroll
    for (int c = 0; c < 8; c++) h0[c] = (_Float16)src[(size_t)c * (Tn * 16384)];
    #pragma unroll
    for (int c = 0; c < 8; c++) h1[c] = (_Float16)src[(size_t)(c + 8) * (Tn * 16384)];
    half8* dst = (half8*)(Xh + (size_t)i * 16);
    dst[0] = h0; dst[1] = h1;
}

// One workgroup per (b, h, w-half): 1024 wgs. 256 threads = 4 waves; wave =
// 1 n-tile (16 w) x 4 oc-tiles. Staging: 1 position/thread (198 used) from
// pre-transposed f16 Xh. 4-slot ring, ONE barrier per t; t+2 prefetch issued
// after the barrier stays in flight across the full compute phase.
//
// LAUNCH_BOUNDS MUST BE (256, 2): the min-waves arg is a VGPR-squeeze target
// for this allocator. Requesting 4 (r9), waves_per_eu(4,4) (r3), or leaving
// dynamic LDS (r2/r5) all made it squeeze 128->64 VGPR and spill ~2.3 GB of
// loop-invariants through HBM (FETCH 2.7-2.9 GB, 2.7x slowdown). With (256,2)
// the allocator lands at <=128 VGPR (r1/r8 evidence) and the RUNTIME occupancy
// is still min(LDS 160/38=4, VGPR@128: 4 waves/SIMD, grid 1024/256) = 4 wg/CU.
__global__ __launch_bounds__(256, 2)
void qrnn_xh_kernel(const _Float16* __restrict__ Xh, const _Float16* __restrict__ WA,
                    const float* __restrict__ bias, float* __restrict__ out) {
    __shared__ __align__(16) char smem[LDSF];

    const int tid  = threadIdx.x;
    const int lane = tid & 63;
    const int wv   = tid >> 6;            // wave 0..3 -> w sub-segment [wv*16, wv*16+16)

    // XCD-bijective swizzle (1024 wgs, 8 XCDs): each XCD gets 64 contiguous h x 2 halves
    const int swz = (blockIdx.x & 7) * 128 + (blockIdx.x >> 3);
    const int b    = swz >> 8;
    const int h    = (swz >> 1) & 127;
    const int wh   = swz & 1;
    const int woff = wh * 64;

    const size_t strideT = (size_t)Hn * Wn;        // 16384
    const size_t strideC = (size_t)Tn * strideT;   // 507904

    const int lane15 = lane & 15;
    const int g      = lane >> 4;         // k-group 0..3
    const int ghi    = g >> 1;            // tap within K-step pair
    const int e      = g & 1;             // cin half
    const int wloc   = wv * 16 + lane15;  // local w column 0..63
    const int pbase  = wloc * POSB + e * 16;

    // bias per thread: hid = g*4 + r (C-frag row = (lane>>4)*4 + reg)
    float bz[4], bfv[4], bov[4], biv[4];
    #pragma unroll
    for (int r = 0; r < 4; r++) {
        int hid = g * 4 + r;
        bz[r]  = bias[hid];
        bfv[r] = bias[HIDn + hid];
        bov[r] = bias[2 * HIDn + hid];
        biv[r] = bias[3 * HIDn + hid];
    }

    // --- staging: 198 positions (3 rows x 66 wpos), exactly one per thread ---
    const char* XhB = (const char*)Xh + (size_t)b * Tn * SLICE_B;
    const bool own  = (tid < NPOS);
    const int  srow = tid / NWPOS;                 // 0..2
    const int  swp  = tid - srow * NWPOS;          // 0..65
    const int  hr   = h - 1 + srow;
    const int  wa   = woff - 1 + swp;              // global w of this position
    const bool inb  = own && (hr >= 0) && (hr < Hn) && (wa >= 0) && (wa < Wn);
    const int  soff = (hr * Wn + wa) * 32;
    const int  loff = srow * ROWF + swp * POSB;

    half8 pfA, pfB;     // in-flight slice data (already f16, no cvt)

    auto issue = [&](int u) {
        half8 a = {}, c = {};
        if (inb && u >= 0 && u < Tn) {
            const char* s = XhB + (size_t)u * SLICE_B + soff;
            a = *reinterpret_cast<const half8*>(s);
            c = *reinterpret_cast<const half8*>(s + 16);
        }
        pfA = a; pfB = c;
    };
    auto commit = [&](int u) {
        if (own) {
            char* dst = smem + (u & 3) * SLOTF + loff;
            *reinterpret_cast<half8*>(dst)      = pfA;
            *reinterpret_cast<half8*>(dst + 16) = pfB;
        }
    };

    // prologue: slot 3 (u=-1) = zeros; commit u=0; issue u=1
    if (own) {
        half8 z = {};
        char* dst = smem + 3 * SLOTF + loff;
        *reinterpret_cast<half8*>(dst)      = z;
        *reinterpret_cast<half8*>(dst + 16) = z;
    }
    issue(0);
    commit(0);
    issue(1);

    float cst[4] = {0.f, 0.f, 0.f, 0.f};
    float* outb = out + (size_t)b * HIDn * strideC + (size_t)h * Wn + woff + wloc;

    for (int t = 0; t < Tn; t++) {
        commit(t + 1);                 // pf (loaded last iter) -> slot (t+1)&3
        __syncthreads();               // lgkm drain publishes it; ring safety
        issue(t + 2);                  // loads in flight across full compute phase

        const int sb[3] = { ((t + 3) & 3) * SLOTF, (t & 3) * SLOTF, ((t + 1) & 3) * SLOTF };

        f32x4 acc[4];
        #pragma unroll
        for (int m = 0; m < 4; m++) acc[m] = (f32x4)(0.f);

        #pragma unroll
        for (int s = 0; s < NS; s++) {
            const half8 a0 = *reinterpret_cast<const half8*>(WA + ((size_t)(s * 4 + 0) * 64 + lane) * 8);
            const half8 a1 = *reinterpret_cast<const half8*>(WA + ((size_t)(s * 4 + 1) * 64 + lane) * 8);
            const half8 a2 = *reinterpret_cast<const half8*>(WA + ((size_t)(s * 4 + 2) * 64 + lane) * 8);
            const half8 a3 = *reinterpret_cast<const half8*>(WA + ((size_t)(s * 4 + 3) * 64 + lane) * 8);

            const int tA = 2 * s, tB = 2 * s + 1;        // compile-time taps
            const int offA = sb[KDt[tA]] + KHt[tA] * ROWF + KWt[tA] * POSB;
            const int offB = sb[KDt[tB]] + KHt[tB] * ROWF + KWt[tB] * POSB;
            const int off  = (ghi ? offB : offA) + pbase;

            const half8 bf = *reinterpret_cast<const half8*>(smem + off);
            acc[0] = __builtin_amdgcn_mfma_f32_16x16x32_f16(a0, bf, acc[0], 0, 0, 0);
            acc[1] = __builtin_amdgcn_mfma_f32_16x16x32_f16(a1, bf, acc[1], 0, 0, 0);
            acc[2] = __builtin_amdgcn_mfma_f32_16x16x32_f16(a2, bf, acc[2], 0, 0, 0);
            acc[3] = __builtin_amdgcn_mfma_f32_16x16x32_f16(a3, bf, acc[3], 0, 0, 0);
        }

        // epilogue: oc-tile m = gate m (z,f,o,i) for hid = g*4+r, col = woff+wloc
        #pragma unroll
        for (int r = 0; r < 4; r++) {
            float z = tanhf_   (acc[0][r] + bz[r]);
            float f = sigmoidf_(acc[1][r] + bfv[r]);
            float o = sigmoidf_(acc[2][r] + bov[r]);
            float i = sigmoidf_(acc[3][r] + biv[r]);
            float c = f * cst[r] + i * z;
            cst[r] = c;
            outb[(size_t)(g * 4 + r) * strideC + (size_t)t * strideT] = o * c;
        }
        // no trailing barrier: 4-slot ring keeps next iter's writes disjoint from
        // any slot a <=1-iteration-lagging wave can still be reading.
    }
}

// =====================  FALLBACK (round-1 harness-verified; used if ws too small)  =====================
#define WSTR  48
#define ROWB  (130*WSTR)
#define SLOT3 (3*ROWB)
#define LDS3  (3*SLOT3)

__global__ __launch_bounds__(256, 2)
void qrnn_fb_kernel(const float* __restrict__ X, const _Float16* __restrict__ WA,
                    const float* __restrict__ bias, float* __restrict__ out) {
    __shared__ __align__(16) char smem[LDS3];
    const int tid  = threadIdx.x;
    const int lane = tid & 63;
    const int wv   = tid >> 6;
    const int swz = (blockIdx.x & 7) * 64 + (blockIdx.x >> 3);
    const int b = swz >> 7;
    const int h = swz & 127;
    const size_t strideT = (size_t)Hn * Wn;
    const size_t strideC = (size_t)Tn * strideT;
    const float* Xb = X + (size_t)b * CINn * strideC;
    const int lane15  = lane & 15;
    const int g       = lane >> 4;
    const int ghi     = g >> 1;
    const int laneoff = lane15 * WSTR + (g & 1) * 16;
    const int wbase   = wv * 32;
    float bz[4], bfv[4], bov[4], biv[4];
    #pragma unroll
    for (int r = 0; r < 4; r++) {
        int hid = g * 4 + r;
        bz[r] = bias[hid]; bfv[r] = bias[HIDn + hid];
        bov[r] = bias[2 * HIDn + hid]; biv[r] = bias[3 * HIDn + hid];
    }
    auto stage = [&](int u, int s) {
        const bool uok = (u >= 0) && (u < Tn);
        for (int p = tid; p < 3 * 130; p += 256) {
            int row  = (p >= 260) ? 2 : (p >= 130) ? 1 : 0;
            int wpos = p - row * 130;
            int hr = h - 1 + row;
            int wa = wpos - 1;
            bool valid = uok && (hr >= 0) && (hr < Hn) && (wa >= 0) && (wa < Wn);
            const float* src = Xb + (ptrdiff_t)u * (ptrdiff_t)strideT + (ptrdiff_t)hr * Wn + wa;
            half8 h0, h1;
            #pragma unroll
            for (int c8 = 0; c8 < 8; c8++) h0[c8] = valid ? (_Float16)src[(size_t)c8 * strideC] : (_Float16)0.f;
            #pragma unroll
            for (int c8 = 0; c8 < 8; c8++) h1[c8] = valid ? (_Float16)src[(size_t)(8 + c8) * strideC] : (_Float16)0.f;
            char* dst = smem + s * SLOT3 + row * ROWB + wpos * WSTR;
            *reinterpret_cast<half8*>(dst)      = h0;
            *reinterpret_cast<half8*>(dst + 16) = h1;
        }
    };
    float cst[2][4];
    #pragma unroll
    for (int n = 0; n < 2; n++)
        #pragma unroll
        for (int r = 0; r < 4; r++) cst[n][r] = 0.f;
    stage(-1, 2);
    stage(0, 0);
    float* outb = out + (size_t)b * HIDn * strideC + (size_t)h * Wn + wbase + lane15;
    for (int t = 0; t < Tn; t++) {
        stage(t + 1, (t + 1) % 3);
        __syncthreads();
        const int sb[3] = { ((t + 2) % 3) * SLOT3, (t % 3) * SLOT3, ((t + 1) % 3) * SLOT3 };
        f32x4 acc[2][4];
        #pragma unroll
        for (int n = 0; n < 2; n++)
            #pragma unroll
            for (int m = 0; m < 4; m++) acc[n][m] = (f32x4)(0.f);
        #pragma unroll
        for (int s = 0; s < NS; s++) {
            const half8 a0 = *reinterpret_cast<const half8*>(WA + ((size_t)(s * 4 + 0) * 64 + lane) * 8);
            const half8 a1 = *reinterpret_cast<const half8*>(WA + ((size_t)(s * 4 + 1) * 64 + lane) * 8);
            const half8 a2 = *reinterpret_cast<const half8*>(WA + ((size_t)(s * 4 + 2) * 64 + lane) * 8);
            const half8 a3 = *reinterpret_cast<const half8*>(WA + ((size_t)(s * 4 + 3) * 64 + lane) * 8);
            const int tA = 2 * s, tB = 2 * s + 1;
            const int offA = sb[KDt[tA]] + KHt[tA] * ROWB + KWt[tA] * WSTR;
            const int offB = sb[KDt[tB]] + KHt[tB] * ROWB + KWt[tB] * WSTR;
            const int off  = (ghi ? offB : offA) + laneoff;
            #pragma unroll
            for (int n = 0; n < 2; n++) {
                const half8 bf = *reinterpret_cast<const half8*>(smem + off + (wbase + n * 16) * WSTR);
                acc[n][0] = __builtin_amdgcn_mfma_f32_16x16x32_f16(a0, bf, acc[n][0], 0, 0, 0);
                acc[n][1] = __builtin_amdgcn_mfma_f32_16x16x32_f16(a1, bf, acc[n][1], 0, 0, 0);
                acc[n][2] = __builtin_amdgcn_mfma_f32_16x16x32_f16(a2, bf, acc[n][2], 0, 0, 0);
                acc[n][3] = __builtin_amdgcn_mfma_f32_16x16x32_f16(a3, bf, acc[n][3], 0, 0, 0);
            }
        }
        #pragma unroll
        for (int n = 0; n < 2; n++) {
            #pragma unroll
            for (int r = 0; r < 4; r++) {
                float z = tanhf_   (acc[n][0][r] + bz[r]);
                float f = sigmoidf_(acc[n][1][r] + bfv[r]);
                float o = sigmoidf_(acc[n][2][r] + bov[r]);
                float i = sigmoidf_(acc[n][3][r] + biv[r]);
                float c = f * cst[n][r] + i * z;
                cst[n][r] = c;
                outb[(size_t)(g * 4 + r) * strideC + (size_t)t * strideT + n * 16] = o * c;
            }
        }
        __syncthreads();
    }
}

// =====================  host  =====================
extern "C" void kernel_launch(void* const* d_in, const int* in_sizes, int n_in,
                              void* d_out, int out_size, void* d_ws, size_t ws_size,
                              hipStream_t stream) {
    const float* X    = (const float*)d_in[0];
    const float* W    = (const float*)d_in[1];
    const float* bias = (const float*)d_in[2];
    float* out = (float*)d_out;

    _Float16* WA = (_Float16*)d_ws;   // 28672 f16 = 57344 BYTES (ends < XH_OFF)
    repack_wa_kernel<<<(NS * 4 * 64 * 8 + 255) / 256, 256, 0, stream>>>(W, WA);

    if (ws_size >= WS_NEED) {
        _Float16* Xh = (_Float16*)((char*)d_ws + XH_OFF);
        transpose_x_kernel<<<(Bn * Tn * Hn * Wn) / 256, 256, 0, stream>>>(X, Xh);
        qrnn_xh_kernel<<<Bn * Hn * 2, 256, 0, stream>>>(Xh, WA, bias, out);
    } else {
        qrnn_fb_kernel<<<Bn * Hn, 256, 0, stream>>>(X, WA, bias, out);
    }
}